// Round 3
// baseline (952.745 us; speedup 1.0000x reference)
//
#include <hip/hip_runtime.h>
#include <hip/hip_fp16.h>

#define TPB 1024

// LDS layout (bytes):
//   Ksh f16 row-major 256x256   [0, 131072)   (staging + one-time extraction only)
//   u2  half2[128]              [131072, 131584)
//   v2  half2[128]              [131584, 132096)
//   a_sh f32[256]               [132096, 133120)
//   b_sh f32[256]               [133120, 134144)
//   scr  f32[32]                [134144, 134272)
#define SMEM_BYTES 134272

typedef _Float16 h2 __attribute__((ext_vector_type(2)));

union HU { unsigned u; h2 h; _Float16 s[2]; };
union QU { uint4 v; h2 h[4]; _Float16 s[8]; };

static __device__ __forceinline__ float dot2(h2 a, h2 b, float c) {
#if defined(__has_builtin)
#if __has_builtin(__builtin_amdgcn_fdot2)
    return __builtin_amdgcn_fdot2(a, b, c, false);
#else
    return fmaf((float)a.x, (float)b.x, fmaf((float)a.y, (float)b.y, c));
#endif
#else
    return fmaf((float)a.x, (float)b.x, fmaf((float)a.y, (float)b.y, c));
#endif
}

// Reduce 8 accumulators across 32 lanes (lane bits 0..4 of l&31).
// Index-partitioned tree: after xor1/xor2/xor4 each lane holds one partial for
// idx = 4*(l&1) + 2*((l>>1)&1) + ((l>>2)&1); xor8/xor16 complete the sum.
static __device__ __forceinline__ float reduce32x8(float acc[8], int l, int* own_idx) {
    const int s0 = l & 1;
    float b4[4];
#pragma unroll
    for (int j = 0; j < 4; ++j) {
        float keep = s0 ? acc[4 + j] : acc[j];
        float send = s0 ? acc[j] : acc[4 + j];
        b4[j] = keep + __shfl_xor(send, 1);
    }
    const int s1 = (l >> 1) & 1;
    float b2[2];
#pragma unroll
    for (int j = 0; j < 2; ++j) {
        float keep = s1 ? b4[2 + j] : b4[j];
        float send = s1 ? b4[j] : b4[2 + j];
        b2[j] = keep + __shfl_xor(send, 2);
    }
    const int s2 = (l >> 2) & 1;
    float keep = s2 ? b2[1] : b2[0];
    float send = s2 ? b2[0] : b2[1];
    float b1 = keep + __shfl_xor(send, 4);
    b1 += __shfl_xor(b1, 8);
    b1 += __shfl_xor(b1, 16);
    *own_idx = 4 * s0 + 2 * s1 + s2;
    return b1;
}

__global__ __launch_bounds__(TPB, 4) void sinkhorn_kernel(
    const float* __restrict__ cost,
    const float* __restrict__ mass_pred,
    const float* __restrict__ mass_target,
    float* __restrict__ out)
{
    extern __shared__ char smem[];
    _Float16* Ksh = (_Float16*)smem;                 // 256 x 256, row-major
    unsigned* u2  = (unsigned*)(smem + 131072);      // 128 half2 (row pairs of u)
    unsigned* v2  = (unsigned*)(smem + 131584);      // 128 half2 (col pairs of v)
    float* a_sh   = (float*)(smem + 132096);
    float* b_sh   = (float*)(smem + 133120);
    float* scr    = (float*)(smem + 134144);

    const int t   = threadIdx.x;
    const int bat = blockIdx.x;
    const int l   = t & 63;
    const int w   = t >> 6;       // wave 0..15
    const int q   = l & 31;       // reduction-axis lane (row-group for A, col-group for B)
    const int g   = l >> 5;       // half-wave 0/1
    const int j   = 2 * w + g;    // A col-block == B row-block, 0..31 (8 elems each)

    //---------------- Phase 0: normalize masses, init u ----------------
    float vmp = 0.f, vmt = 0.f;
    if (t < 256) {
        vmp = mass_pred [bat * 256 + t];
        vmt = mass_target[bat * 256 + t];
    }
    float s1 = vmp, s2r = vmt;
#pragma unroll
    for (int o = 32; o > 0; o >>= 1) {
        s1  += __shfl_xor(s1, o);
        s2r += __shfl_xor(s2r, o);
    }
    if (t < 256 && l == 0) { scr[w] = s1; scr[8 + w] = s2r; }
    if (t < 128) {
        HU one; one.h = (h2){(_Float16)1.f, (_Float16)1.f};
        u2[t] = one.u;
    }
    __syncthreads();
    if (t == 0) {
        float ta = 0.f, tb = 0.f;
#pragma unroll
        for (int ww = 0; ww < 4; ++ww) { ta += scr[ww]; tb += scr[8 + ww]; }
        scr[16] = ta + 1e-8f;
        scr[17] = tb + 1e-8f;
    }
    __syncthreads();
    if (t < 256) {
        a_sh[t] = vmp / scr[16];
        b_sh[t] = vmt / scr[17];
    }

    //---------------- Phase 1: K = exp(-C/eps) -> f16 row-major LDS ------
    {
        const float4* C4 = (const float4*)(cost + (size_t)bat * 65536);
#pragma unroll 4
        for (int i = 0; i < 16; ++i) {
            int idx = i * TPB + t;       // float4 index: row = idx>>6, col4 = idx&63
            float4 c = C4[idx];
            int n = idx >> 6, col4 = idx & 63;
            HU p01, p23;
            p01.h = (h2){(_Float16)__expf(c.x * -10.0f), (_Float16)__expf(c.y * -10.0f)};
            p23.h = (h2){(_Float16)__expf(c.z * -10.0f), (_Float16)__expf(c.w * -10.0f)};
            *(uint2*)((char*)Ksh + n * 512 + col4 * 8) = make_uint2(p01.u, p23.u);
        }
    }
    __syncthreads();

    //---------------- One-time extraction into registers -----------------
    // A-slice (pass A, K^T u): rows [8q,8q+8), cols [8j,8j+8),
    //   packed along rows: apk[p][c] = (K[8q+2p][8j+c], K[8q+2p+1][8j+c])
    h2 apk[4][8];
#pragma unroll
    for (int p = 0; p < 4; ++p) {
        QU r0, r1;
        r0.v = *(const uint4*)((const char*)Ksh + (8 * q + 2 * p) * 512 + j * 16);
        r1.v = *(const uint4*)((const char*)Ksh + (8 * q + 2 * p + 1) * 512 + j * 16);
#pragma unroll
        for (int c = 0; c < 8; ++c)
            apk[p][c] = (h2){r0.s[c], r1.s[c]};
    }
    // B-slice (pass B, K v): rows [8j,8j+8), cols [8q,8q+8),
    //   naturally packed along cols: bpk[i][c] = (K[8j+i][8q+2c], K[8j+i][8q+2c+1])
    h2 bpk[8][4];
#pragma unroll
    for (int i = 0; i < 8; ++i) {
        QU rr;
        rr.v = *(const uint4*)((const char*)Ksh + (8 * j + i) * 512 + q * 16);
#pragma unroll
        for (int c = 0; c < 4; ++c) bpk[i][c] = rr.h[c];
    }
    __syncthreads();

    //---------------- Phase 2: 100 Sinkhorn iterations --------------------
    for (int it = 0; it < 100; ++it) {
        // ---- Pass A: Ktu[m] = sum_n K[n][m] u[n];  v = b/(Ktu+eps)
        QU ua;
        ua.v = *(const uint4*)(u2 + 4 * q);     // u rows [8q,8q+8) as 4 half2
        float acc[8];
#pragma unroll
        for (int c = 0; c < 8; ++c) acc[c] = 0.f;
#pragma unroll
        for (int p = 0; p < 4; ++p) {
#pragma unroll
            for (int c = 0; c < 8; ++c)
                acc[c] = dot2(apk[p][c], ua.h[p], acc[c]);
        }
        int idx;
        float ktu = reduce32x8(acc, l, &idx);
        {
            int col = 8 * j + idx;
            float vv = b_sh[col] * __builtin_amdgcn_rcpf(ktu + 1e-8f);
            float vp = __shfl_xor(vv, 4);       // partner holds idx^1
            HU hv;
            hv.h = ((l >> 2) & 1) ? (h2){(_Float16)vp, (_Float16)vv}
                                  : (h2){(_Float16)vv, (_Float16)vp};
            if ((l & 28) == 0)                  // 8 writer lanes per wave
                v2[4 * j + (idx >> 1)] = hv.u;
        }
        __syncthreads();

        // ---- Pass B: Kv[n] = sum_m K[n][m] v[m];  u = a/(Kv+eps)
        QU vb;
        vb.v = *(const uint4*)(v2 + 4 * q);     // v cols [8q,8q+8) as 4 half2
        float accb[8];
#pragma unroll
        for (int i = 0; i < 8; ++i) accb[i] = 0.f;
#pragma unroll
        for (int i = 0; i < 8; ++i) {
#pragma unroll
            for (int c = 0; c < 4; ++c)
                accb[i] = dot2(bpk[i][c], vb.h[c], accb[i]);
        }
        int idxb;
        float kv = reduce32x8(accb, l, &idxb);
        {
            int row = 8 * j + idxb;
            float uu = a_sh[row] * __builtin_amdgcn_rcpf(kv + 1e-8f);
            float up = __shfl_xor(uu, 4);
            HU hu;
            hu.h = ((l >> 2) & 1) ? (h2){(_Float16)up, (_Float16)uu}
                                  : (h2){(_Float16)uu, (_Float16)up};
            if ((l & 28) == 0)
                u2[4 * j + (idxb >> 1)] = hu.u;
        }
        __syncthreads();
    }

    //---------------- Phase 3: cost = sum u K v C, C = -eps log K ---------
    float s = 0.f;
    {
        QU uu, vv0;
        uu.v  = *(const uint4*)(u2 + 4 * q);   // u rows [8q,8q+8) as pairs
        vv0.v = *(const uint4*)(v2 + 4 * j);   // v cols [8j,8j+8) as pairs
        float vcol[8];
#pragma unroll
        for (int c = 0; c < 4; ++c) {
            vcol[2 * c]     = (float)vv0.h[c].x;
            vcol[2 * c + 1] = (float)vv0.h[c].y;
        }
#pragma unroll
        for (int p = 0; p < 4; ++p) {
            float u0 = (float)uu.h[p].x, u1 = (float)uu.h[p].y;
#pragma unroll
            for (int c = 0; c < 8; ++c) {
                float k0 = (float)apk[p][c].x;
                float k1 = (float)apk[p][c].y;
                float c0 = -0.1f * __logf(k0);
                float c1 = -0.1f * __logf(k1);
                s = fmaf(u0 * k0 * c0, vcol[c], s);
                s = fmaf(u1 * k1 * c1, vcol[c], s);
            }
        }
    }
#pragma unroll
    for (int o = 32; o > 0; o >>= 1) s += __shfl_xor(s, o);
    if (l == 0) scr[w] = s;
    __syncthreads();
    if (t == 0) {
        float tot = 0.f;
#pragma unroll
        for (int ww = 0; ww < 16; ++ww) tot += scr[ww];
        atomicAdd(out, tot * (1.0f / 1024.0f));
    }
}

extern "C" void kernel_launch(void* const* d_in, const int* in_sizes, int n_in,
                              void* d_out, int out_size, void* d_ws, size_t ws_size,
                              hipStream_t stream) {
    const float* cost = (const float*)d_in[0];
    const float* mp   = (const float*)d_in[1];
    const float* mt   = (const float*)d_in[2];
    float* out = (float*)d_out;

    // out is re-poisoned to 0xAA before every timed launch -> zero it
    hipMemsetAsync(out, 0, sizeof(float), stream);

    // >64KB dynamic LDS: opt in (gfx950 has 160KB/CU)
    hipFuncSetAttribute((const void*)sinkhorn_kernel,
                        hipFuncAttributeMaxDynamicSharedMemorySize, SMEM_BYTES);

    sinkhorn_kernel<<<1024, TPB, SMEM_BYTES, stream>>>(cost, mp, mt, out);
}

// Round 4
// 723.457 us; speedup vs baseline: 1.3169x; 1.3169x over previous
//
#include <hip/hip_runtime.h>

#define TPB 1024

// LDS layout (bytes):
//   Ksh f16 row-major 256x256   [0, 131072)   (staging + one-time extraction only)
//   uh  f16[256]                [131072, 131584)
//   vh  f16[256]                [131584, 132096)
//   a_sh f32[256]               [132096, 133120)
//   b_sh f32[256]               [133120, 134144)
//   scr  f32[32]                [134144, 134272)
#define SMEM_BYTES 134272

typedef _Float16 f16x8 __attribute__((ext_vector_type(8)));
typedef _Float16 f16x4 __attribute__((ext_vector_type(4)));
typedef _Float16 h2    __attribute__((ext_vector_type(2)));
typedef float    f32x4 __attribute__((ext_vector_type(4)));

union HU { unsigned u; h2 h; };

__global__ __launch_bounds__(TPB, 4) void sinkhorn_kernel(
    const float* __restrict__ cost,
    const float* __restrict__ mass_pred,
    const float* __restrict__ mass_target,
    float* __restrict__ out)
{
    extern __shared__ char smem[];
    _Float16* Ksh = (_Float16*)smem;                 // 256 x 256, row-major
    _Float16* uh  = (_Float16*)(smem + 131072);      // u as f16[256]
    _Float16* vh  = (_Float16*)(smem + 131584);      // v as f16[256]
    float* a_sh   = (float*)(smem + 132096);
    float* b_sh   = (float*)(smem + 133120);
    float* scr    = (float*)(smem + 134144);

    const int t    = threadIdx.x;
    const int bat  = blockIdx.x;
    const int l    = t & 63;
    const int w    = t >> 6;        // wave 0..15; wave tile = rows [16w, 16w+16)
    const int quad = (l >> 4) & 3;  // MFMA quad group
    const int col  = l & 15;        // MFMA column lane
    const int row0 = 16 * w + quad * 4;   // rows this lane's D regs cover

    //---------------- Phase 0: normalize masses, init u ----------------
    float vmp = 0.f, vmt = 0.f;
    if (t < 256) {
        vmp = mass_pred [bat * 256 + t];
        vmt = mass_target[bat * 256 + t];
    }
    float s1 = vmp, s2 = vmt;
#pragma unroll
    for (int o = 32; o > 0; o >>= 1) {
        s1 += __shfl_xor(s1, o);
        s2 += __shfl_xor(s2, o);
    }
    if (t < 256 && l == 0) { scr[w] = s1; scr[8 + w] = s2; }
    if (t < 256) uh[t] = (_Float16)1.0f;
    __syncthreads();
    if (t == 0) {
        float ta = 0.f, tb = 0.f;
#pragma unroll
        for (int ww = 0; ww < 4; ++ww) { ta += scr[ww]; tb += scr[8 + ww]; }
        scr[16] = ta + 1e-8f;
        scr[17] = tb + 1e-8f;
    }
    __syncthreads();
    if (t < 256) {
        a_sh[t] = vmp / scr[16];
        b_sh[t] = vmt / scr[17];
    }

    //---------------- Phase 1: K = exp(-C/eps) -> f16 row-major LDS ------
    {
        const float4* C4 = (const float4*)(cost + (size_t)bat * 65536);
#pragma unroll 4
        for (int i = 0; i < 16; ++i) {
            int idx = i * TPB + t;       // float4 index: row = idx>>6, col4 = idx&63
            float4 c = C4[idx];
            int n = idx >> 6, col4 = idx & 63;
            HU p01, p23;
            p01.h = (h2){(_Float16)__expf(c.x * -10.0f), (_Float16)__expf(c.y * -10.0f)};
            p23.h = (h2){(_Float16)__expf(c.z * -10.0f), (_Float16)__expf(c.w * -10.0f)};
            *(uint2*)((char*)Ksh + n * 512 + col4 * 8) = make_uint2(p01.u, p23.u);
        }
    }
    __syncthreads();   // Ksh ready; also publishes uh/a_sh/b_sh

    //---------------- One-time fragment extraction ------------------------
    // Pass-A (K^T u): A-frag afrag[c], lane layout A[m=col][k=quad*8+j],
    //   m_global = 16w+col (target index), k_global = n = 32c+quad*8+j (source row).
    //   afrag[c][j] = K[32c+quad*8+j][16w+col]  (column reads, one-time)
    f16x8 afrag[8];
#pragma unroll
    for (int c = 0; c < 8; ++c) {
#pragma unroll
        for (int j = 0; j < 8; ++j)
            afrag[c][j] = Ksh[(32 * c + quad * 8 + j) * 256 + 16 * w + col];
    }
    // Pass-B (K v): A-frag bfrag[c][j] = K[16w+col][32c+quad*8+j] (row-contig b128)
    f16x8 bfrag[8];
#pragma unroll
    for (int c = 0; c < 8; ++c)
        bfrag[c] = *(const f16x8*)&Ksh[(16 * w + col) * 256 + 32 * c + quad * 8];

    //---------------- Phase 2: 100 Sinkhorn iterations --------------------
    for (int it = 0; it < 100; ++it) {
        // ---- Pass A: Ktu = K^T u via MFMA, B = u broadcast across columns
        f32x4 acc = {0.f, 0.f, 0.f, 0.f};
#pragma unroll
        for (int c = 0; c < 8; ++c) {
            f16x8 uf = *(const f16x8*)&uh[32 * c + quad * 8];  // same for all col
            acc = __builtin_amdgcn_mfma_f32_16x16x32_f16(afrag[c], uf, acc, 0, 0, 0);
        }
        // D[row=quad*4+r][*] = Ktu[16w+quad*4+r] in every column lane
        {
            f32x4 bb = *(const f32x4*)&b_sh[row0];
            f16x4 vr;
#pragma unroll
            for (int r = 0; r < 4; ++r)
                vr[r] = (_Float16)(bb[r] * __builtin_amdgcn_rcpf(acc[r] + 1e-8f));
            if (col == 0) *(f16x4*)&vh[row0] = vr;
        }
        __syncthreads();

        // ---- Pass B: Kv = K v via MFMA, B = v broadcast across columns
        f32x4 accb = {0.f, 0.f, 0.f, 0.f};
#pragma unroll
        for (int c = 0; c < 8; ++c) {
            f16x8 vf = *(const f16x8*)&vh[32 * c + quad * 8];
            accb = __builtin_amdgcn_mfma_f32_16x16x32_f16(bfrag[c], vf, accb, 0, 0, 0);
        }
        {
            f32x4 aa = *(const f32x4*)&a_sh[row0];
            f16x4 ur;
#pragma unroll
            for (int r = 0; r < 4; ++r)
                ur[r] = (_Float16)(aa[r] * __builtin_amdgcn_rcpf(accb[r] + 1e-8f));
            if (col == 0) *(f16x4*)&uh[row0] = ur;
        }
        __syncthreads();
    }

    //---------------- Phase 3: cost = sum u K v C, C = -eps log K ---------
    // bfrag[c][j] = K[n][k], n = 16w+col, k = 32c+quad*8+j. Each (n,k) covered
    // exactly once across lanes/waves.
    float s = 0.f;
    {
        float uN = (float)uh[16 * w + col];
#pragma unroll
        for (int c = 0; c < 8; ++c) {
            f16x8 vf = *(const f16x8*)&vh[32 * c + quad * 8];
#pragma unroll
            for (int j = 0; j < 8; ++j) {
                float kv = (float)bfrag[c][j];
                float cv = -0.1f * __logf(kv);
                s = fmaf(kv * cv, (float)vf[j], s);
            }
        }
        s *= uN;
    }
#pragma unroll
    for (int o = 32; o > 0; o >>= 1) s += __shfl_xor(s, o);
    if (l == 0) scr[w] = s;
    __syncthreads();
    if (t == 0) {
        float tot = 0.f;
#pragma unroll
        for (int ww = 0; ww < 16; ++ww) tot += scr[ww];
        atomicAdd(out, tot * (1.0f / 1024.0f));
    }
}

extern "C" void kernel_launch(void* const* d_in, const int* in_sizes, int n_in,
                              void* d_out, int out_size, void* d_ws, size_t ws_size,
                              hipStream_t stream) {
    const float* cost = (const float*)d_in[0];
    const float* mp   = (const float*)d_in[1];
    const float* mt   = (const float*)d_in[2];
    float* out = (float*)d_out;

    // out is re-poisoned to 0xAA before every timed launch -> zero it
    hipMemsetAsync(out, 0, sizeof(float), stream);

    // >64KB dynamic LDS: opt in (gfx950 has 160KB/CU)
    hipFuncSetAttribute((const void*)sinkhorn_kernel,
                        hipFuncAttributeMaxDynamicSharedMemorySize, SMEM_BYTES);

    sinkhorn_kernel<<<1024, TPB, SMEM_BYTES, stream>>>(cost, mp, mt, out);
}

// Round 5
// 699.383 us; speedup vs baseline: 1.3623x; 1.0344x over previous
//
#include <hip/hip_runtime.h>

#define TPB 1024

// LDS layout (bytes):
//   Ksh f16 row-major 256x256   [0, 131072)   (staging + one-time extraction only)
//   uh  f16[256]                [131072, 131584)
//   vh  f16[256]                [131584, 132096)
//   a_sh f32[256]               [132096, 133120)
//   b_sh f32[256]               [133120, 134144)
//   scr  f32[32]                [134144, 134272)
#define SMEM_BYTES 134272

typedef _Float16 f16x8 __attribute__((ext_vector_type(8)));
typedef _Float16 f16x4 __attribute__((ext_vector_type(4)));
typedef _Float16 h2    __attribute__((ext_vector_type(2)));
typedef float    f32x4 __attribute__((ext_vector_type(4)));

union HU { unsigned u; h2 h; };

// Select element (c & 3) of a f32x4 accumulator with 2 cndmasks.
static __device__ __forceinline__ float sel4(f32x4 a, int c) {
    float x01 = (c & 1) ? a[1] : a[0];
    float x23 = (c & 1) ? a[3] : a[2];
    return (c & 2) ? x23 : x01;
}

__global__ __launch_bounds__(TPB, 4) void sinkhorn_kernel(
    const float* __restrict__ cost,
    const float* __restrict__ mass_pred,
    const float* __restrict__ mass_target,
    float* __restrict__ out)
{
    extern __shared__ char smem[];
    _Float16* Ksh = (_Float16*)smem;                 // 256 x 256, row-major
    _Float16* uh  = (_Float16*)(smem + 131072);      // u as f16[256]
    _Float16* vh  = (_Float16*)(smem + 131584);      // v as f16[256]
    float* a_sh   = (float*)(smem + 132096);
    float* b_sh   = (float*)(smem + 133120);
    float* scr    = (float*)(smem + 134144);

    const int t    = threadIdx.x;
    const int bat  = blockIdx.x;
    const int l    = t & 63;
    const int w    = t >> 6;        // wave 0..15; wave tile = rows [16w, 16w+16)
    const int quad = (l >> 4) & 3;  // MFMA quad group
    const int col  = l & 15;        // MFMA column lane
    // lane (quad, col<4) owns output element row 16w + 4*quad + col
    const int own  = 16 * w + 4 * quad + (col & 3);

    //---------------- Phase 0: normalize masses, init u ----------------
    float vmp = 0.f, vmt = 0.f;
    if (t < 256) {
        vmp = mass_pred [bat * 256 + t];
        vmt = mass_target[bat * 256 + t];
    }
    float s1 = vmp, s2 = vmt;
#pragma unroll
    for (int o = 32; o > 0; o >>= 1) {
        s1 += __shfl_xor(s1, o);
        s2 += __shfl_xor(s2, o);
    }
    if (t < 256 && l == 0) { scr[w] = s1; scr[8 + w] = s2; }
    if (t < 256) uh[t] = (_Float16)1.0f;
    __syncthreads();
    if (t == 0) {
        float ta = 0.f, tb = 0.f;
#pragma unroll
        for (int ww = 0; ww < 4; ++ww) { ta += scr[ww]; tb += scr[8 + ww]; }
        scr[16] = ta + 1e-8f;
        scr[17] = tb + 1e-8f;
    }
    __syncthreads();
    if (t < 256) {
        a_sh[t] = vmp / scr[16];
        b_sh[t] = vmt / scr[17];
    }

    //---------------- Phase 1: K = exp(-C/eps) -> f16 row-major LDS ------
    {
        const float4* C4 = (const float4*)(cost + (size_t)bat * 65536);
#pragma unroll 4
        for (int i = 0; i < 16; ++i) {
            int idx = i * TPB + t;       // float4 index: row = idx>>6, col4 = idx&63
            float4 c = C4[idx];
            int n = idx >> 6, col4 = idx & 63;
            HU p01, p23;
            p01.h = (h2){(_Float16)__expf(c.x * -10.0f), (_Float16)__expf(c.y * -10.0f)};
            p23.h = (h2){(_Float16)__expf(c.z * -10.0f), (_Float16)__expf(c.w * -10.0f)};
            *(uint2*)((char*)Ksh + n * 512 + col4 * 8) = make_uint2(p01.u, p23.u);
        }
    }
    __syncthreads();   // Ksh ready; also publishes uh/a_sh/b_sh

    //---------------- One-time fragment extraction ------------------------
    // Pass-A (K^T u): afrag[c][j] = K[32c+quad*8+j][16w+col]  (A-layout of K^T)
    f16x8 afrag[8];
#pragma unroll
    for (int c = 0; c < 8; ++c) {
#pragma unroll
        for (int j = 0; j < 8; ++j)
            afrag[c][j] = Ksh[(32 * c + quad * 8 + j) * 256 + 16 * w + col];
    }
    // Pass-B (K v): bfrag[c][j] = K[16w+col][32c+quad*8+j] (row-contig b128)
    f16x8 bfrag[8];
#pragma unroll
    for (int c = 0; c < 8; ++c)
        bfrag[c] = *(const f16x8*)&Ksh[(16 * w + col) * 256 + 32 * c + quad * 8];

    //---------------- Phase 2: 100 Sinkhorn iterations --------------------
    for (int it = 0; it < 100; ++it) {
        // ---- Pass A: Ktu = K^T u via MFMA (B = u broadcast across columns)
        {
            float bb = b_sh[own];                  // prefetch before the chain
            f16x8 uf0 = *(const f16x8*)&uh[quad * 8];
            f16x8 uf1 = *(const f16x8*)&uh[32 + quad * 8];
            f16x8 uf2 = *(const f16x8*)&uh[64 + quad * 8];
            f16x8 uf3 = *(const f16x8*)&uh[96 + quad * 8];
            f16x8 uf4 = *(const f16x8*)&uh[128 + quad * 8];
            f16x8 uf5 = *(const f16x8*)&uh[160 + quad * 8];
            f16x8 uf6 = *(const f16x8*)&uh[192 + quad * 8];
            f16x8 uf7 = *(const f16x8*)&uh[224 + quad * 8];
            f32x4 c0 = {0.f, 0.f, 0.f, 0.f}, c1 = c0, c2 = c0, c3 = c0;
            c0 = __builtin_amdgcn_mfma_f32_16x16x32_f16(afrag[0], uf0, c0, 0, 0, 0);
            c1 = __builtin_amdgcn_mfma_f32_16x16x32_f16(afrag[1], uf1, c1, 0, 0, 0);
            c2 = __builtin_amdgcn_mfma_f32_16x16x32_f16(afrag[2], uf2, c2, 0, 0, 0);
            c3 = __builtin_amdgcn_mfma_f32_16x16x32_f16(afrag[3], uf3, c3, 0, 0, 0);
            c0 = __builtin_amdgcn_mfma_f32_16x16x32_f16(afrag[4], uf4, c0, 0, 0, 0);
            c1 = __builtin_amdgcn_mfma_f32_16x16x32_f16(afrag[5], uf5, c1, 0, 0, 0);
            c2 = __builtin_amdgcn_mfma_f32_16x16x32_f16(afrag[6], uf6, c2, 0, 0, 0);
            c3 = __builtin_amdgcn_mfma_f32_16x16x32_f16(afrag[7], uf7, c3, 0, 0, 0);
            float kt = (sel4(c0, col) + sel4(c1, col)) +
                       (sel4(c2, col) + sel4(c3, col));
            float vvv = bb * __builtin_amdgcn_rcpf(kt + 1e-8f);
            if (col < 4) vh[own] = (_Float16)vvv;
        }
        __syncthreads();

        // ---- Pass B: Kv = K v via MFMA (B = v broadcast across columns)
        {
            float aa = a_sh[own];
            f16x8 vf0 = *(const f16x8*)&vh[quad * 8];
            f16x8 vf1 = *(const f16x8*)&vh[32 + quad * 8];
            f16x8 vf2 = *(const f16x8*)&vh[64 + quad * 8];
            f16x8 vf3 = *(const f16x8*)&vh[96 + quad * 8];
            f16x8 vf4 = *(const f16x8*)&vh[128 + quad * 8];
            f16x8 vf5 = *(const f16x8*)&vh[160 + quad * 8];
            f16x8 vf6 = *(const f16x8*)&vh[192 + quad * 8];
            f16x8 vf7 = *(const f16x8*)&vh[224 + quad * 8];
            f32x4 c0 = {0.f, 0.f, 0.f, 0.f}, c1 = c0, c2 = c0, c3 = c0;
            c0 = __builtin_amdgcn_mfma_f32_16x16x32_f16(bfrag[0], vf0, c0, 0, 0, 0);
            c1 = __builtin_amdgcn_mfma_f32_16x16x32_f16(bfrag[1], vf1, c1, 0, 0, 0);
            c2 = __builtin_amdgcn_mfma_f32_16x16x32_f16(bfrag[2], vf2, c2, 0, 0, 0);
            c3 = __builtin_amdgcn_mfma_f32_16x16x32_f16(bfrag[3], vf3, c3, 0, 0, 0);
            c0 = __builtin_amdgcn_mfma_f32_16x16x32_f16(bfrag[4], vf4, c0, 0, 0, 0);
            c1 = __builtin_amdgcn_mfma_f32_16x16x32_f16(bfrag[5], vf5, c1, 0, 0, 0);
            c2 = __builtin_amdgcn_mfma_f32_16x16x32_f16(bfrag[6], vf6, c2, 0, 0, 0);
            c3 = __builtin_amdgcn_mfma_f32_16x16x32_f16(bfrag[7], vf7, c3, 0, 0, 0);
            float kv = (sel4(c0, col) + sel4(c1, col)) +
                       (sel4(c2, col) + sel4(c3, col));
            float uuu = aa * __builtin_amdgcn_rcpf(kv + 1e-8f);
            if (col < 4) uh[own] = (_Float16)uuu;
        }
        __syncthreads();
    }

    //---------------- Phase 3: cost = sum u K v C, C = -eps log K ---------
    // bfrag[c][j] = K[n][k], n = 16w+col, k = 32c+quad*8+j. Each (n,k) covered
    // exactly once across lanes/waves.
    float s = 0.f;
    {
        float uN = (float)uh[16 * w + col];
#pragma unroll
        for (int c = 0; c < 8; ++c) {
            f16x8 vf = *(const f16x8*)&vh[32 * c + quad * 8];
#pragma unroll
            for (int j = 0; j < 8; ++j) {
                float kv = (float)bfrag[c][j];
                float cv = -0.1f * __logf(kv);
                s = fmaf(kv * cv, (float)vf[j], s);
            }
        }
        s *= uN;
    }
#pragma unroll
    for (int o = 32; o > 0; o >>= 1) s += __shfl_xor(s, o);
    if (l == 0) scr[w] = s;
    __syncthreads();
    if (t == 0) {
        float tot = 0.f;
#pragma unroll
        for (int ww = 0; ww < 16; ++ww) tot += scr[ww];
        atomicAdd(out, tot * (1.0f / 1024.0f));
    }
}

extern "C" void kernel_launch(void* const* d_in, const int* in_sizes, int n_in,
                              void* d_out, int out_size, void* d_ws, size_t ws_size,
                              hipStream_t stream) {
    const float* cost = (const float*)d_in[0];
    const float* mp   = (const float*)d_in[1];
    const float* mt   = (const float*)d_in[2];
    float* out = (float*)d_out;

    // out is re-poisoned to 0xAA before every timed launch -> zero it
    hipMemsetAsync(out, 0, sizeof(float), stream);

    // >64KB dynamic LDS: opt in (gfx950 has 160KB/CU)
    hipFuncSetAttribute((const void*)sinkhorn_kernel,
                        hipFuncAttributeMaxDynamicSharedMemorySize, SMEM_BYTES);

    sinkhorn_kernel<<<1024, TPB, SMEM_BYTES, stream>>>(cost, mp, mt, out);
}